// Round 3
// baseline (866.726 us; speedup 1.0000x reference)
//
#include <hip/hip_runtime.h>

typedef __attribute__((ext_vector_type(4))) float f32x4;
typedef __attribute__((ext_vector_type(2))) float f32x2;
typedef __attribute__((ext_vector_type(8))) short s16x8;

static __device__ __forceinline__ unsigned short f2bf(float f) {
  unsigned int u = __builtin_bit_cast(unsigned int, f);
  u += 0x7fffu + ((u >> 16) & 1u);   // round-to-nearest-even
  return (unsigned short)(u >> 16);
}
static __device__ __forceinline__ float bf2f(unsigned short h) {
  unsigned int u = ((unsigned int)h) << 16;
  return __builtin_bit_cast(float, u);
}

static __device__ __forceinline__ void gload_lds16(const void* g, void* l) {
  __builtin_amdgcn_global_load_lds(
      (const __attribute__((address_space(1))) unsigned int*)g,
      (__attribute__((address_space(3))) unsigned int*)l, 16, 0, 0);
}

// ---------------- utility ----------------
__global__ void zero_k(int* p, int n) {
  int i = blockIdx.x * 256 + threadIdx.x;
  if (i < n) p[i] = 0;
}
__global__ void deg_count_k(const int* __restrict__ edges, int* cnt, int E) {
  int e = blockIdx.x * 256 + threadIdx.x;
  if (e < E) atomicAdd(&cnt[edges[E + e]], 1);
}

// ---------------- prefix scan (exclusive) over cnt -> row offsets ----------------
__global__ __launch_bounds__(256) void scan1_k(const int* __restrict__ cnt,
                                               int* __restrict__ loc,
                                               int* __restrict__ bsum, int N) {
  int t = threadIdx.x;
  int i0 = blockIdx.x * 1024 + t * 4;
  int c[4];
#pragma unroll
  for (int j = 0; j < 4; ++j) c[j] = (i0 + j < N) ? cnt[i0 + j] : 0;
  int tsum = c[0] + c[1] + c[2] + c[3];
  int lane = t & 63, wv = t >> 6;
  int incl = tsum;
#pragma unroll
  for (int off = 1; off < 64; off <<= 1) {
    int u = __shfl_up(incl, off, 64);
    if (lane >= off) incl += u;
  }
  __shared__ int ws[4];
  if (lane == 63) ws[wv] = incl;
  __syncthreads();
  int wbase = 0;
  for (int w = 0; w < wv; ++w) wbase += ws[w];
  int run = wbase + incl - tsum;
#pragma unroll
  for (int j = 0; j < 4; ++j) {
    if (i0 + j < N) loc[i0 + j] = run;
    run += c[j];
  }
  if (t == 255) bsum[blockIdx.x] = wbase + incl;
}
__global__ void scan2_k(int* bsum, int nb) {
  int lane = threadIdx.x;
  int v = (lane < nb) ? bsum[lane] : 0;
  int incl = v;
#pragma unroll
  for (int off = 1; off < 64; off <<= 1) {
    int u = __shfl_up(incl, off, 64);
    if (lane >= off) incl += u;
  }
  if (lane < nb) bsum[lane] = incl - v;
}
// add block offsets + init cursor + compute dinv (fused)
__global__ void addoff_k(int* loc, int* cursor, const int* __restrict__ bsum,
                         const int* __restrict__ cnt, float* __restrict__ dinv, int N) {
  int i = blockIdx.x * 256 + threadIdx.x;
  if (i < N) {
    int v = loc[i] + bsum[i >> 10];
    loc[i] = v;
    cursor[i] = v;
    dinv[i] = rsqrtf((float)(cnt[i] + 1));   // +1 self-loop
  }
}
__global__ void fill_k(const int* __restrict__ edges, int* cursor,
                       int* __restrict__ csr, int E) {
  int e = blockIdx.x * 256 + threadIdx.x;
  if (e < E) {
    int s = edges[e], d = edges[E + e];
    int pos = atomicAdd(&cursor[d], 1);
    csr[pos] = s;
  }
}

// ---------------- weight transpose + bf16 convert (LDS-tiled, both sides coalesced) ----------------
// Wt[n][k] = bf16(W[k][n]); grid (K/32, Nn/32), 256 threads = 32x8
__global__ __launch_bounds__(256) void convw_k(const float* __restrict__ W,
                                               unsigned short* __restrict__ Wt,
                                               int K, int Nn) {
  __shared__ float t[32][33];
  const int tx = threadIdx.x & 31, ty = threadIdx.x >> 5;
  const int k0 = blockIdx.x * 32, n0 = blockIdx.y * 32;
#pragma unroll
  for (int r = 0; r < 32; r += 8)
    t[r + ty][tx] = W[(long long)(k0 + r + ty) * Nn + (n0 + tx)];
  __syncthreads();
#pragma unroll
  for (int r = 0; r < 32; r += 8)
    Wt[(long long)(n0 + r + ty) * K + (k0 + tx)] = f2bf(t[tx][r + ty]);
}

// ---------------- bf16 MFMA GEMM ----------------
// Output NODE-MAJOR: outg[m][n] = bf16( dinv[m] * (A @ Bt^T)[m][n] ).
// A_BF16=false: A fp32 (layer 1, A=x). A_BF16=true: A bf16 (layer 2, A=acc1).
// B (and A when bf16) staged via global_load_lds with XOR slot swizzle:
//   content at LDS (row, slot s) = src[row][(s ^ ((row>>1)&3))*8 ..], rows of 32 shorts (64B).
template <int KTOT, int NTOT, int BM, bool A_BF16>
__global__ __launch_bounds__(256, 3) void gemm_k(
    const void* __restrict__ Aptr, const unsigned short* __restrict__ Bt,
    const float* __restrict__ dinv, unsigned short* __restrict__ outg, int M) {
  constexpr int BK = 32;
  constexpr int LDA = BK + 8;            // fp32-path A LDS row stride (shorts)
  constexpr int MI = BM / 16;            // M fragments per wave
  constexpr int STRIP = NTOT / 4;
  constexpr int NF = STRIP / 16;
  constexpr int BCH = (NTOT / 16) / 4;   // 1KB B-chunks per wave (16 rows each)
  constexpr int ACH = (BM / 16) / 4;     // 1KB A-chunks per wave (bf16 path)
  constexpr int NT = KTOT / BK;
  constexpr int TPR = 256 / BM;          // threads per A-row (fp32 path)
  constexpr int FPT = BK / TPR;          // floats per thread (fp32 path)

  __shared__ unsigned short Asm_[2][BM * LDA];
  __shared__ unsigned short Bsm_[2][NTOT * BK];

  const int tid = threadIdx.x;
  const int wave = tid >> 6;
  const int lane = tid & 63;
  const int fr = lane & 15;
  const int quad = lane >> 4;
  const int m0 = blockIdx.x * BM;

  f32x4 acc[MI][NF];
#pragma unroll
  for (int i = 0; i < MI; ++i)
#pragma unroll
    for (int j = 0; j < NF; ++j) { f32x4 z = {0.f, 0.f, 0.f, 0.f}; acc[i][j] = z; }

  // stage helpers: lane -> (row-in-chunk, swizzled source slot)
  const int sl_r = lane >> 2;
  const int sl_s = (lane & 3) ^ ((lane >> 3) & 3);

  auto stageB = [&](int k0, int buf) {
#pragma unroll
    for (int c = 0; c < BCH; ++c) {
      int cc = wave * BCH + c;
      int r = cc * 16 + sl_r;
      const unsigned short* gp = Bt + (long long)r * KTOT + k0 + sl_s * 8;
      gload_lds16(gp, &Bsm_[buf][cc * 512]);
    }
  };
  auto stageA_h = [&](int k0, int buf) {
    const unsigned short* Ah = (const unsigned short*)Aptr;
#pragma unroll
    for (int c = 0; c < ACH; ++c) {
      int cc = wave * ACH + c;
      int r = cc * 16 + sl_r;
      const unsigned short* gp = Ah + (long long)(m0 + r) * KTOT + k0 + sl_s * 8;
      gload_lds16(gp, &Asm_[buf][cc * 512]);
    }
  };

  // fp32 A path: regs -> convert -> ds_write (padded layout)
  const int sr = tid / TPR;
  const int sc = (tid % TPR) * FPT;
  const bool arow_ok = (m0 + sr) < M;
  const float* arowf = (const float*)Aptr + (long long)(m0 + sr) * KTOT;
  float va[FPT];
  auto loadA = [&](int k0) {
    if (arow_ok) {
#pragma unroll
      for (int c = 0; c < FPT / 4; ++c) {
        f32x4 v = *(const f32x4*)(arowf + k0 + sc + c * 4);
#pragma unroll
        for (int j = 0; j < 4; ++j) va[c * 4 + j] = v[j];
      }
    } else {
#pragma unroll
      for (int j = 0; j < FPT; ++j) va[j] = 0.0f;
    }
  };
  auto cvtWriteA = [&](int buf) {
#pragma unroll
    for (int c = 0; c < FPT / 8; ++c) {
      s16x8 h;
#pragma unroll
      for (int j = 0; j < 8; ++j) h[j] = (short)f2bf(va[c * 8 + j]);
      *(s16x8*)&Asm_[buf][sr * LDA + sc + c * 8] = h;
    }
  };

  // prologue: stage tile 0
  stageB(0, 0);
  if constexpr (A_BF16) {
    stageA_h(0, 0);
  } else {
    loadA(0);
    cvtWriteA(0);
    if (NT > 1) loadA(BK);
  }

  const int xsl = (fr >> 1) & 3;
  for (int kt = 0; kt < NT; ++kt) {
    const int cur = kt & 1;
    __syncthreads();   // drains vm (stage of cur) + lgkm (A writes of cur)
    if (kt + 1 < NT) {
      stageB((kt + 1) * BK, cur ^ 1);
      if constexpr (A_BF16) {
        stageA_h((kt + 1) * BK, cur ^ 1);
      } else {
        cvtWriteA(cur ^ 1);                    // consumes va(kt+1)
        if (kt + 2 < NT) loadA((kt + 2) * BK); // prefetch next-next
      }
    }

    s16x8 af[MI], bfr[NF];
#pragma unroll
    for (int mi = 0; mi < MI; ++mi) {
      if constexpr (A_BF16)
        af[mi] = *(const s16x8*)&Asm_[cur][(mi * 16 + fr) * BK + ((quad ^ xsl) << 3)];
      else
        af[mi] = *(const s16x8*)&Asm_[cur][(mi * 16 + fr) * LDA + quad * 8];
    }
#pragma unroll
    for (int ni = 0; ni < NF; ++ni)
      bfr[ni] = *(const s16x8*)&Bsm_[cur][(wave * STRIP + ni * 16 + fr) * BK + ((quad ^ xsl) << 3)];
#pragma unroll
    for (int mi = 0; mi < MI; ++mi)
#pragma unroll
      for (int ni = 0; ni < NF; ++ni)
        acc[mi][ni] = __builtin_amdgcn_mfma_f32_16x16x32_bf16(af[mi], bfr[ni], acc[mi][ni], 0, 0, 0);
  }

  // epilogue: C/D layout col=lane&15, row=quad*4+r; write node-major
#pragma unroll
  for (int mi = 0; mi < MI; ++mi) {
    int mbase = mi * 16 + quad * 4;
#pragma unroll
    for (int r = 0; r < 4; ++r) {
      int gm = m0 + mbase + r;
      if (gm < M) {
        float dv = dinv[gm];
#pragma unroll
        for (int ni = 0; ni < NF; ++ni) {
          int col = wave * STRIP + ni * 16 + fr;
          outg[(long long)gm * NTOT + col] = f2bf(acc[mi][ni][r] * dv);
        }
      }
    }
  }
}

// ---------------- agg layer 1: one wave per node, 2 row-groups x 32 lanes x 16B ----------------
// acc1[d][0..256) = bf16(relu(b1 + dinv[d]*(g[d] + sum g[src])))
__global__ __launch_bounds__(256) void agg1_k(const int* __restrict__ csr,
                                              const int* __restrict__ row,
                                              const int* __restrict__ cnt,
                                              const unsigned short* __restrict__ g,
                                              const float* __restrict__ bias,
                                              const float* __restrict__ dinv,
                                              unsigned short* __restrict__ h, int N) {
  const int wave = threadIdx.x >> 6, lane = threadIdx.x & 63;
  const int node = blockIdx.x * 4 + wave;
  if (node >= N) return;
  const int grp = lane >> 5, sub = lane & 31;
  const int f0 = sub * 8;                       // 8 feats = 16B per lane
  float s[8];
#pragma unroll
  for (int k = 0; k < 8; ++k) s[k] = 0.0f;
  const int start = row[node], len = cnt[node];
  int j = 0;
  for (; j + 8 <= len; j += 8) {                // 8 neighbors: 4 gathers x 2 rows
    int idx[4];
#pragma unroll
    for (int t = 0; t < 4; ++t) idx[t] = csr[start + j + t * 2 + grp];
    s16x8 v[4];
#pragma unroll
    for (int t = 0; t < 4; ++t) v[t] = *(const s16x8*)&g[(long long)idx[t] * 256 + f0];
#pragma unroll
    for (int t = 0; t < 4; ++t)
#pragma unroll
      for (int k = 0; k < 8; ++k) s[k] += bf2f((unsigned short)v[t][k]);
  }
  for (; j < len; j += 2) {                     // masked tail, 2 rows per iter
    int jt = j + grp;
    bool val = jt < len;
    int idx = csr[start + (val ? jt : 0)];
    s16x8 v = *(const s16x8*)&g[(long long)idx * 256 + f0];
    float m = val ? 1.0f : 0.0f;
#pragma unroll
    for (int k = 0; k < 8; ++k) s[k] += m * bf2f((unsigned short)v[k]);
  }
  // cross-group reduce (groups of 32)
#pragma unroll
  for (int k = 0; k < 8; ++k) s[k] += __shfl_xor(s[k], 32, 64);
  // self row (added once, post-reduce)
  s16x8 sv = *(const s16x8*)&g[(long long)node * 256 + f0];
#pragma unroll
  for (int k = 0; k < 8; ++k) s[k] += bf2f((unsigned short)sv[k]);
  const float dv = dinv[node];
  f32x4 b0 = *(const f32x4*)&bias[f0];
  f32x4 b1v = *(const f32x4*)&bias[f0 + 4];
  if (grp == 0) {
    s16x8 o;
#pragma unroll
    for (int k = 0; k < 4; ++k) o[k] = (short)f2bf(fmaxf(0.0f, b0[k] + dv * s[k]));
#pragma unroll
    for (int k = 0; k < 4; ++k) o[4 + k] = (short)f2bf(fmaxf(0.0f, b1v[k] + dv * s[4 + k]));
    *(s16x8*)&h[(long long)node * 256 + f0] = o;
  }
}

// ---------------- agg layer 2 + fused L2-normalize: one wave per node, 4 groups x 16 lanes x 16B ----------------
__global__ __launch_bounds__(256) void agg2_k(const int* __restrict__ csr,
                                              const int* __restrict__ row,
                                              const int* __restrict__ cnt,
                                              const unsigned short* __restrict__ g,
                                              const float* __restrict__ b2,
                                              const float* __restrict__ dinv,
                                              float* __restrict__ out, int N) {
  const int wave = threadIdx.x >> 6, lane = threadIdx.x & 63;
  const int node = blockIdx.x * 4 + wave;
  if (node >= N) return;
  const int grp = lane >> 4, sub = lane & 15;
  const int f0 = sub * 8;                       // 8 feats = 16B per lane
  float s[8];
#pragma unroll
  for (int k = 0; k < 8; ++k) s[k] = 0.0f;
  const int start = row[node], len = cnt[node];
  int j = 0;
  for (; j + 8 <= len; j += 8) {                // 8 neighbors: 2 gathers x 4 rows
    int idx[2];
#pragma unroll
    for (int t = 0; t < 2; ++t) idx[t] = csr[start + j + t * 4 + grp];
    s16x8 v[2];
#pragma unroll
    for (int t = 0; t < 2; ++t) v[t] = *(const s16x8*)&g[(long long)idx[t] * 128 + f0];
#pragma unroll
    for (int t = 0; t < 2; ++t)
#pragma unroll
      for (int k = 0; k < 8; ++k) s[k] += bf2f((unsigned short)v[t][k]);
  }
  for (; j < len; j += 4) {                     // masked tail, 4 rows per iter
    int jt = j + grp;
    bool val = jt < len;
    int idx = csr[start + (val ? jt : 0)];
    s16x8 v = *(const s16x8*)&g[(long long)idx * 128 + f0];
    float m = val ? 1.0f : 0.0f;
#pragma unroll
    for (int k = 0; k < 8; ++k) s[k] += m * bf2f((unsigned short)v[k]);
  }
  // cross-group reduce (4 groups of 16)
#pragma unroll
  for (int k = 0; k < 8; ++k) s[k] += __shfl_xor(s[k], 16, 64);
#pragma unroll
  for (int k = 0; k < 8; ++k) s[k] += __shfl_xor(s[k], 32, 64);
  // self row (added once, post-reduce)
  s16x8 sv = *(const s16x8*)&g[(long long)node * 128 + f0];
#pragma unroll
  for (int k = 0; k < 8; ++k) s[k] += bf2f((unsigned short)sv[k]);
  const float dv = dinv[node];
  f32x4 b0 = *(const f32x4*)&b2[f0];
  f32x4 b1v = *(const f32x4*)&b2[f0 + 4];
  float x[8];
#pragma unroll
  for (int k = 0; k < 4; ++k) x[k] = b0[k] + dv * s[k];
#pragma unroll
  for (int k = 0; k < 4; ++k) x[4 + k] = b1v[k] + dv * s[4 + k];
  float ss = 0.0f;
#pragma unroll
  for (int k = 0; k < 8; ++k) ss += x[k] * x[k];
  // norm reduce across the 16 lanes of the group (all groups identical)
#pragma unroll
  for (int off = 1; off < 16; off <<= 1) ss += __shfl_xor(ss, off, 64);
  const float inv = 1.0f / fmaxf(sqrtf(ss), 1e-12f);
  if (grp == 0) {
    f32x4 o0 = {x[0] * inv, x[1] * inv, x[2] * inv, x[3] * inv};
    f32x4 o1 = {x[4] * inv, x[5] * inv, x[6] * inv, x[7] * inv};
    *(f32x4*)&out[(long long)node * 128 + f0] = o0;
    *(f32x4*)&out[(long long)node * 128 + f0 + 4] = o1;
  }
}

extern "C" void kernel_launch(void* const* d_in, const int* in_sizes, int n_in,
                              void* d_out, int out_size, void* d_ws, size_t ws_size,
                              hipStream_t stream) {
  const float* x = (const float*)d_in[0];
  const int* edges = (const int*)d_in[1];
  const float* W1 = (const float*)d_in[2];
  const float* b1 = (const float*)d_in[3];
  const float* W2 = (const float*)d_in[4];
  const float* b2 = (const float*)d_in[5];
  float* out = (float*)d_out;

  const int HID = in_sizes[3];          // 256
  const int OUT = in_sizes[5];          // 128
  const int IN = in_sizes[2] / HID;     // 1536
  const int N = in_sizes[0] / IN;       // 50000
  const int E = in_sizes[1] / 2;        // 1600000

  size_t off = 0;
  auto carve = [&](size_t bytes) {
    void* p = (char*)d_ws + off;
    off += (bytes + 255) & ~(size_t)255;
    return p;
  };
  int* cnt = (int*)carve((size_t)N * 4);
  int* cursor = (int*)carve((size_t)N * 4);
  int* row = (int*)carve((size_t)N * 4);
  int* bsum = (int*)carve(64 * 4);
  int* csr = (int*)carve((size_t)E * 4 + 1024);
  float* dinv = (float*)carve((size_t)N * 4);
  unsigned short* W1t = (unsigned short*)carve((size_t)IN * HID * 2);
  unsigned short* W2t = (unsigned short*)carve((size_t)HID * OUT * 2);
  unsigned short* g1 = (unsigned short*)carve((size_t)N * HID * 2);    // node-major [N][256]
  unsigned short* acc1 = (unsigned short*)carve((size_t)N * HID * 2);  // node-major [N][256]
  unsigned short* g2 = (unsigned short*)carve((size_t)N * OUT * 2);    // node-major [N][128]
  (void)ws_size; (void)n_in; (void)out_size;

  const int nb = (N + 1023) / 1024;

  zero_k<<<(N + 255) / 256, 256, 0, stream>>>(cnt, N);
  deg_count_k<<<(E + 255) / 256, 256, 0, stream>>>(edges, cnt, E);

  scan1_k<<<nb, 256, 0, stream>>>(cnt, row, bsum, N);
  scan2_k<<<1, 64, 0, stream>>>(bsum, nb);
  addoff_k<<<(N + 255) / 256, 256, 0, stream>>>(row, cursor, bsum, cnt, dinv, N);
  fill_k<<<(E + 255) / 256, 256, 0, stream>>>(edges, cursor, csr, E);

  convw_k<<<dim3(IN / 32, HID / 32), 256, 0, stream>>>(W1, W1t, IN, HID);
  convw_k<<<dim3(HID / 32, OUT / 32), 256, 0, stream>>>(W2, W2t, HID, OUT);

  constexpr int BM = 64;
  int mtiles = (N + BM - 1) / BM;
  gemm_k<1536, 256, BM, false><<<mtiles, 256, 0, stream>>>(x, W1t, dinv, g1, N);
  agg1_k<<<(N + 3) / 4, 256, 0, stream>>>(csr, row, cnt, g1, b1, dinv, acc1, N);
  gemm_k<256, 128, BM, true><<<mtiles, 256, 0, stream>>>(acc1, W2t, dinv, g2, N);
  agg2_k<<<(N + 3) / 4, 256, 0, stream>>>(csr, row, cnt, g2, b2, dinv, out, N);
}